// Round 5
// baseline (1289.549 us; speedup 1.0000x reference)
//
#include <hip/hip_runtime.h>

#define H    32
#define SEQ  1440
#define NT   (SEQ - 1)   // step 1439 is dead code (only h2[:, :1439] is consumed)
#define INP  11
#define TC   64          // timesteps per chunk (x staging + deferred FC)

#define LOG2E 1.44269504f

__device__ __forceinline__ float rcp_fast(float x)  { return __builtin_amdgcn_rcpf(x); }
__device__ __forceinline__ float exp2_fast(float x) { return __builtin_amdgcn_exp2f(x); }
__device__ __forceinline__ float tanh_f(float x) {
    // tanh(x) = 2/(1+exp2(-2*log2e*x)) - 1
    return fmaf(2.f, rcp_fast(1.f + exp2_fast(x * (-2.f * LOG2E))), -1.f);
}
// Pin a value in a VGPR: no load left to rematerialize, so the allocator must
// keep it live (budget 256 via waves_per_eu(2,2) -> no scratch spill either).
__device__ __forceinline__ void pin(float& v) { asm volatile("" : "+v"(v)); }

// Block = 128 threads (2 waves) = one batch sample.
// Thread (wave wv, lane l): gate q = l>>4 (i/f/g/o), hidden jj = wv*16 + (l&15).
// Weight row r = q*32+jj held in registers, pre-scaled by log2e (and 2x for the
// g-gate) so the activation is: act = am * rcp(1 + exp2(-a)) + ab.
__global__
__attribute__((amdgpu_flat_work_group_size(128, 128)))
__attribute__((amdgpu_waves_per_eu(2, 2)))
void lstm_fused_kernel(const float* __restrict__ x,
                       const float* __restrict__ Wih0, const float* __restrict__ Whh0,
                       const float* __restrict__ bih0, const float* __restrict__ bhh0,
                       const float* __restrict__ Wih1, const float* __restrict__ Whh1,
                       const float* __restrict__ bih1, const float* __restrict__ bhh1,
                       const float* __restrict__ fc1w_g, const float* __restrict__ fc1b_g,
                       const float* __restrict__ fc2w_g, const float* __restrict__ fc2b_g,
                       float* __restrict__ out)
{
    __shared__ float h0s[2][H];      // double-buffered layer-0 h
    __shared__ float h1s[2][H];      // double-buffered layer-1 h
    __shared__ float xs[TC][12];     // x chunk [t][i], padded 11->12
    __shared__ float h1c[TC][36];    // layer-1 h history for deferred FC (+pad)

    const int tid  = threadIdx.x;
    const int lane = tid & 63;
    const int wv   = tid >> 6;
    const int m    = lane & 15;
    const int q    = lane >> 4;
    const int jj   = wv * 16 + m;
    const int r    = q * 32 + jj;
    const int b    = blockIdx.x;

    const float gsl = ((q == 2) ? 2.f : 1.f) * LOG2E;   // fold tanh 2x + log2e
    const float am  = (q == 2) ? 2.f : 1.f;
    const float ab  = (q == 2) ? -1.f : 0.f;

    // ---- weights -> registers (pre-scaled), pinned resident for the kernel ----
    float wx[12];
    #pragma unroll
    for (int i = 0; i < INP; ++i) { wx[i] = Wih0[r * INP + i] * gsl; pin(wx[i]); }
    wx[11] = 0.f;
    float wh0[H], wi1[H], wh1[H];
    #pragma unroll
    for (int k = 0; k < H; ++k) {
        wh0[k] = Whh0[r * H + k] * gsl; pin(wh0[k]);
        wi1[k] = Wih1[r * H + k] * gsl; pin(wi1[k]);
        wh1[k] = Whh1[r * H + k] * gsl; pin(wh1[k]);
    }
    float bs0 = (bih0[r] + bhh0[r]) * gsl; pin(bs0);
    float bs1 = (bih1[r] + bhh1[r]) * gsl; pin(bs1);

    if (tid < H) { h0s[0][tid] = 0.f; h1s[0][tid] = 0.f; }
    float c0 = 0.f, c1 = 0.f;

    const float* xb   = x   + (size_t)b * INP * SEQ;   // x[b][i][t], t contiguous
    float*       outb = out + (size_t)b * NT;

    __syncthreads();

    for (int cbase = 0; cbase < NT; cbase += TC) {
        const int clen = min(TC, NT - cbase);

        // ---- stage x[b][:, cbase:cbase+clen] into LDS (coalesced over t) ----
        {
            const int col = tid & 63;
            const int rw  = tid >> 6;
            #pragma unroll
            for (int ib = 0; ib < 12; ib += 2) {
                const int row = ib + rw;
                if (col < clen)
                    xs[col][row] = (row < INP) ? xb[row * SEQ + cbase + col] : 0.f;
            }
        }
        __syncthreads();

        for (int tc = 0; tc < clen; ++tc) {
            const int p = (cbase + tc) & 1;   // h double-buffer parity

            // ================= layer 0 =================
            float act;
            {
                const float4* xv = (const float4*)xs[tc];
                const float4* hv = (const float4*)h0s[p];
                float a0 = bs0, a1 = 0.f;
                float4 x0 = xv[0], x1 = xv[1], x2 = xv[2];
                a0 = fmaf(wx[0],  x0.x, a0);  a1 = fmaf(wx[1],  x0.y, a1);
                a0 = fmaf(wx[2],  x0.z, a0);  a1 = fmaf(wx[3],  x0.w, a1);
                a0 = fmaf(wx[4],  x1.x, a0);  a1 = fmaf(wx[5],  x1.y, a1);
                a0 = fmaf(wx[6],  x1.z, a0);  a1 = fmaf(wx[7],  x1.w, a1);
                a0 = fmaf(wx[8],  x2.x, a0);  a1 = fmaf(wx[9],  x2.y, a1);
                a0 = fmaf(wx[10], x2.z, a0);
                #pragma unroll
                for (int kk = 0; kk < 4; ++kk) {
                    float4 ha = hv[kk], hb = hv[kk + 4];
                    a0 = fmaf(wh0[4*kk+0],    ha.x, a0);
                    a1 = fmaf(wh0[4*kk+1],    ha.y, a1);
                    a0 = fmaf(wh0[4*kk+2],    ha.z, a0);
                    a1 = fmaf(wh0[4*kk+3],    ha.w, a1);
                    a0 = fmaf(wh0[16+4*kk+0], hb.x, a0);
                    a1 = fmaf(wh0[16+4*kk+1], hb.y, a1);
                    a0 = fmaf(wh0[16+4*kk+2], hb.z, a0);
                    a1 = fmaf(wh0[16+4*kk+3], hb.w, a1);
                }
                float a = a0 + a1;
                act = fmaf(am, rcp_fast(1.f + exp2_fast(-a)), ab);
            }
            // gates i,f,g,o live at lanes l, l+16, l+32, l+48 of this wave
            float gf = __shfl_xor(act, 16);
            float gg = __shfl_xor(act, 32);
            float go = __shfl_xor(act, 48);
            if (q == 0) {
                c0 = fmaf(gf, c0, act * gg);
                h0s[p ^ 1][jj] = go * tanh_f(c0);
            }
            __syncthreads();   // new h0 visible to both waves

            // ================= layer 1 =================
            {
                const float4* hav = (const float4*)h0s[p ^ 1];  // input = new h0
                const float4* hbv = (const float4*)h1s[p];      // recurrent = old h1
                float a0 = bs1, a1 = 0.f, a2 = 0.f, a3 = 0.f;
                #pragma unroll
                for (int kk = 0; kk < 4; ++kk) {
                    float4 ha = hav[kk], ha2 = hav[kk + 4];
                    float4 hb = hbv[kk], hb2 = hbv[kk + 4];
                    a0 = fmaf(wi1[4*kk+0],    ha.x,  a0); a1 = fmaf(wi1[4*kk+1],    ha.y,  a1);
                    a2 = fmaf(wi1[4*kk+2],    ha.z,  a2); a3 = fmaf(wi1[4*kk+3],    ha.w,  a3);
                    a0 = fmaf(wi1[16+4*kk+0], ha2.x, a0); a1 = fmaf(wi1[16+4*kk+1], ha2.y, a1);
                    a2 = fmaf(wi1[16+4*kk+2], ha2.z, a2); a3 = fmaf(wi1[16+4*kk+3], ha2.w, a3);
                    a0 = fmaf(wh1[4*kk+0],    hb.x,  a0); a1 = fmaf(wh1[4*kk+1],    hb.y,  a1);
                    a2 = fmaf(wh1[4*kk+2],    hb.z,  a2); a3 = fmaf(wh1[4*kk+3],    hb.w,  a3);
                    a0 = fmaf(wh1[16+4*kk+0], hb2.x, a0); a1 = fmaf(wh1[16+4*kk+1], hb2.y, a1);
                    a2 = fmaf(wh1[16+4*kk+2], hb2.z, a2); a3 = fmaf(wh1[16+4*kk+3], hb2.w, a3);
                }
                float a = (a0 + a1) + (a2 + a3);
                act = fmaf(am, rcp_fast(1.f + exp2_fast(-a)), ab);
            }
            gf = __shfl_xor(act, 16);
            gg = __shfl_xor(act, 32);
            go = __shfl_xor(act, 48);
            if (q == 0) {
                c1 = fmaf(gf, c1, act * gg);
                float hn = go * tanh_f(c1);
                h1s[p ^ 1][jj] = hn;
                h1c[tc][jj]    = hn;   // history for deferred FC
            }
            __syncthreads();   // h1/h1c visible
        }

        // ---- deferred FC head: 16 units x clen steps, all 128 threads ----
        // FC weights are chunk-local: NOT live across the main step loop.
        {
            const int u = tid & 15;
            float fcw[H];
            #pragma unroll
            for (int k = 0; k < H; ++k) fcw[k] = fc1w_g[u * H + k];
            const float fcb = fc1b_g[u];
            const float f2w = fc2w_g[u];
            const float f2b = fc2b_g[0];
            #pragma unroll
            for (int rep = 0; rep < 8; ++rep) {
                const int tcl = (tid >> 4) + 8 * rep;   // uniform within 16-lane group
                if (tcl < clen) {
                    const float4* hv = (const float4*)h1c[tcl];
                    float a0 = fcb, a1 = 0.f;
                    #pragma unroll
                    for (int kk = 0; kk < 4; ++kk) {
                        float4 ha = hv[kk], hb = hv[kk + 4];
                        a0 = fmaf(fcw[4*kk+0],    ha.x, a0); a1 = fmaf(fcw[4*kk+1],    ha.y, a1);
                        a0 = fmaf(fcw[4*kk+2],    ha.z, a0); a1 = fmaf(fcw[4*kk+3],    ha.w, a1);
                        a0 = fmaf(fcw[16+4*kk+0], hb.x, a0); a1 = fmaf(fcw[16+4*kk+1], hb.y, a1);
                        a0 = fmaf(fcw[16+4*kk+2], hb.z, a0); a1 = fmaf(fcw[16+4*kk+3], hb.w, a1);
                    }
                    float yv = tanh_f(a0 + a1) * f2w;
                    yv += __shfl_xor(yv, 1);
                    yv += __shfl_xor(yv, 2);
                    yv += __shfl_xor(yv, 4);
                    yv += __shfl_xor(yv, 8);
                    if (u == 0) outb[cbase + tcl] = yv + f2b;
                }
            }
        }
        __syncthreads();   // h1c reads done before next chunk's steps overwrite
    }
}

extern "C" void kernel_launch(void* const* d_in, const int* in_sizes, int n_in,
                              void* d_out, int out_size, void* d_ws, size_t ws_size,
                              hipStream_t stream)
{
    const float* x    = (const float*)d_in[0];
    const float* Wih0 = (const float*)d_in[1];
    const float* Whh0 = (const float*)d_in[2];
    const float* bih0 = (const float*)d_in[3];
    const float* bhh0 = (const float*)d_in[4];
    const float* Wih1 = (const float*)d_in[5];
    const float* Whh1 = (const float*)d_in[6];
    const float* bih1 = (const float*)d_in[7];
    const float* bhh1 = (const float*)d_in[8];
    const float* fc1w = (const float*)d_in[9];
    const float* fc1b = (const float*)d_in[10];
    const float* fc2w = (const float*)d_in[11];
    const float* fc2b = (const float*)d_in[12];
    float* out = (float*)d_out;

    const int B = in_sizes[0] / (INP * SEQ);   // 1024
    dim3 grid(B), block(128);
    hipLaunchKernelGGL(lstm_fused_kernel, grid, block, 0, stream,
                       x, Wih0, Whh0, bih0, bhh0, Wih1, Whh1, bih1, bhh1,
                       fc1w, fc1b, fc2w, fc2b, out);
}